// Round 2
// baseline (638.516 us; speedup 1.0000x reference)
//
#include <hip/hip_runtime.h>
#include <math.h>

typedef __attribute__((ext_vector_type(4))) float f32x4;
typedef _Float16 f16;
typedef __attribute__((ext_vector_type(8))) _Float16 f16x8;

// Problem constants (DeepSeek-V3 gate: hidden (4,2048,7168), 256 experts)
constexpr int H       = 7168;
constexpr int E       = 256;
constexpr int T_TOTAL = 8192;     // 4*2048 tokens

constexpr int KSPLIT  = 4;
constexpr int K_SLICE = H / KSPLIT;    // 1792
constexpr int NCH     = K_SLICE / 64;  // 28 chunks of BK=64
constexpr int NPAIR   = NCH / 2;       // 14 barrier periods (BK=128 per sync)
constexpr int MT      = 64;            // tokens per GEMM block (4 mtiles)
constexpr int NMB     = T_TOTAL / MT;  // 128 token-tiles (fixup counters)

constexpr int N_GROUP    = 8;
constexpr int TOPK_GROUP = 4;
constexpr int TOP_K      = 8;

constexpr size_t SCORES_OFF = 8u * 1024 * 1024;    // ws: wf at 0 (7.34MB)
constexpr size_t CNT_OFF    = 48u * 1024 * 1024;   // 128 uint counters

// ---------------------------------------------------------------------------
// Kernel 1: split w (fp32) into f16 hi/lo in MFMA B-fragment order:
//   wf[((kc*16 + ntile)*2 + s)*512 + lane*8 + j]
//   kc = h>>5, ntile = e>>4, s = 0(hi)/1(lo), lane = ((h>>3)&3)<<4 | (e&15)
// Also zeroes the split-K fixup counters (workspace is re-poisoned every
// iteration, so they must be cleared in-stream before the GEMM runs).
// ---------------------------------------------------------------------------
__global__ __launch_bounds__(64) void pack_w_kernel(const float* __restrict__ w,
                                                    f16* __restrict__ wf,
                                                    unsigned* __restrict__ cnt)
{
    const int l  = threadIdx.x;
    if (blockIdx.x == 0) {
        #pragma unroll
        for (int i = 0; i < NMB / 64; ++i) cnt[i * 64 + l] = 0u;
    }
    const int nt = blockIdx.x & 15;
    const int kc = blockIdx.x >> 4;
    const int e  = nt * 16 + (l & 15);
    const int h  = kc * 32 + (l >> 4) * 8;
    const float* src = &w[(size_t)e * H + h];
    f32x4 v0 = *reinterpret_cast<const f32x4*>(src);
    f32x4 v1 = *reinterpret_cast<const f32x4*>(src + 4);
    float v[8] = {v0[0], v0[1], v0[2], v0[3], v1[0], v1[1], v1[2], v1[3]};
    f16x8 hi, lo;
    #pragma unroll
    for (int j = 0; j < 8; ++j) {
        f16 h16 = (f16)v[j];
        hi[j] = h16;
        lo[j] = (f16)(v[j] - (float)h16);
    }
    const size_t base = (((size_t)kc * 16 + nt) * 2) * 512 + (size_t)l * 8;
    *reinterpret_cast<f16x8*>(&wf[base])       = hi;
    *reinterpret_cast<f16x8*>(&wf[base + 512]) = lo;
}

// ---------------------------------------------------------------------------
// Kernel 2: router GEMM + fused split-K gate fixup.
// GEMM internals identical to the verified kernel (absmax 0 anchor):
//   grid 512 = 64 M-tiles x 4 K-slices; 8 waves; 64m x 256n block tile;
//   f16-split MFMA (hihi, hilo, lohi per 32-k step); 14 lgkm-only barriers.
// New: after the epilogue each block fences + bumps cnt[mb]; the 4th
// arrival runs the gate for its 64 tokens (verbatim gate math), reading
// partials that are hot in L2/L3 instead of a separate serial kernel.
// ---------------------------------------------------------------------------
__global__ __launch_bounds__(512, 4) void gemm_kernel(
    const float* __restrict__ x,      // [T_TOTAL, H] fp32
    const f16*   __restrict__ wf,     // packed B-fragments
    float* __restrict__ scores,       // [T_TOTAL][KSPLIT][E] partial logits
    const float* __restrict__ bias,   // [E]
    float* __restrict__ out,          // [T*8 idx][T*8 weight]
    unsigned* __restrict__ cnt)       // [NMB] fixup counters (pre-zeroed)
{
    // [buf][half][mtile 0..3][ks 0..1][s 0..1][lane 0..63][j 0..7] = 64 KB
    __shared__ __align__(16) f16 x_lds[2][2][4 * 2 * 2 * 512];
    __shared__ int sh_last;

    const int tid  = threadIdx.x;
    const int lane = tid & 63;
    const int wn   = tid >> 6;     // wave 0..7: experts wn*32 .. +31

    const int bid = blockIdx.x;
    const int ksl = bid & 3;
    const int mb  = bid >> 2;      // 0..63
    const int t0  = mb * MT;
    const int k0  = ksl * K_SLICE;
    const int kc0 = k0 >> 5;       // first K-chunk-of-32 index

    // x loader: tid -> (mtile, ks, lane); 8 floats per thread per chunk
    const int lmt = (tid >> 6) & 3;
    const int lks = tid >> 8;                 // 0..1
    const float* xrow = &x[(size_t)(t0 + lmt * 16 + (lane & 15)) * H
                           + k0 + lks * 32 + (lane >> 4) * 8];

    const int lm = lane & 15;
    const int kq = lane >> 4;

    f32x4 acc[4][2];
    #pragma unroll
    for (int mt = 0; mt < 4; ++mt)
        #pragma unroll
        for (int nt = 0; nt < 2; ++nt)
            acc[mt][nt] = (f32x4){0.f, 0.f, 0.f, 0.f};

    // stage this thread's 8 floats as hi/lo fragments into LDS
    auto stage = [&](int bu, int half, f32x4 v0, f32x4 v1) {
        float v[8] = {v0[0], v0[1], v0[2], v0[3], v1[0], v1[1], v1[2], v1[3]};
        f16x8 hi, lo;
        #pragma unroll
        for (int j = 0; j < 8; ++j) {
            f16 h16 = (f16)v[j];
            hi[j] = h16;
            lo[j] = (f16)(v[j] - (float)h16);
        }
        f16* base = &x_lds[bu][half][((lmt * 2 + lks) * 2) * 512 + lane * 8];
        *reinterpret_cast<f16x8*>(base)       = hi;
        *reinterpret_cast<f16x8*>(base + 512) = lo;
    };

    auto load_b = [&](f16x8 (&b)[2][2], int kc) {
        #pragma unroll
        for (int nt = 0; nt < 2; ++nt)
            #pragma unroll
            for (int s = 0; s < 2; ++s)
                b[nt][s] = *reinterpret_cast<const f16x8*>(
                    &wf[(((size_t)kc * 16 + wn * 2 + nt) * 2 + s) * 512 + lane * 8]);
    };

    // per-mtile A fragments: 8 transient VGPRs; per-acc order is
    // hihi, hilo, lohi within each 32-k step (identical numerics)
    auto mfma_step = [&](const f16x8 (&b)[2][2], int bu, int half, int ks) {
        #pragma unroll
        for (int mt = 0; mt < 4; ++mt) {
            const f16* ap = &x_lds[bu][half][((mt * 2 + ks) * 2) * 512 + lane * 8];
            f16x8 ahi = *reinterpret_cast<const f16x8*>(ap);
            f16x8 alo = *reinterpret_cast<const f16x8*>(ap + 512);
            acc[mt][0] = __builtin_amdgcn_mfma_f32_16x16x32_f16(ahi, b[0][0], acc[mt][0], 0, 0, 0);
            acc[mt][1] = __builtin_amdgcn_mfma_f32_16x16x32_f16(ahi, b[1][0], acc[mt][1], 0, 0, 0);
            acc[mt][0] = __builtin_amdgcn_mfma_f32_16x16x32_f16(ahi, b[0][1], acc[mt][0], 0, 0, 0);
            acc[mt][1] = __builtin_amdgcn_mfma_f32_16x16x32_f16(ahi, b[1][1], acc[mt][1], 0, 0, 0);
            acc[mt][0] = __builtin_amdgcn_mfma_f32_16x16x32_f16(alo, b[0][0], acc[mt][0], 0, 0, 0);
            acc[mt][1] = __builtin_amdgcn_mfma_f32_16x16x32_f16(alo, b[1][0], acc[mt][1], 0, 0, 0);
        }
    };

    f16x8 b0[2][2], b1[2][2];

    // prologue: stage chunks 0,1 into buf 0; preload first B step
    {
        f32x4 v0 = *reinterpret_cast<const f32x4*>(xrow);
        f32x4 v1 = *reinterpret_cast<const f32x4*>(xrow + 4);
        f32x4 v2 = *reinterpret_cast<const f32x4*>(xrow + 64);
        f32x4 v3 = *reinterpret_cast<const f32x4*>(xrow + 68);
        stage(0, 0, v0, v1);
        stage(0, 1, v2, v3);
    }
    load_b(b0, kc0);
    __syncthreads();

    for (int i = 0; i < NPAIR; ++i) {
        const int buf   = i & 1;
        const int kbase = kc0 + i * 4;
        const bool last = (i + 1 == NPAIR);

        // prefetch next pair of x chunks into registers
        f32x4 nva0, nva1, nvb0, nvb1;
        if (!last) {
            const float* nx = xrow + (2 * i + 2) * 64;
            nva0 = *reinterpret_cast<const f32x4*>(nx);
            nva1 = *reinterpret_cast<const f32x4*>(nx + 4);
            nvb0 = *reinterpret_cast<const f32x4*>(nx + 64);
            nvb1 = *reinterpret_cast<const f32x4*>(nx + 68);
        }

        // B register pipeline across the 4 K-steps of this pair
        load_b(b1, kbase + 1);
        __builtin_amdgcn_s_setprio(1);
        mfma_step(b0, buf, 0, 0);
        load_b(b0, kbase + 2);
        mfma_step(b1, buf, 0, 1);
        load_b(b1, kbase + 3);
        mfma_step(b0, buf, 1, 0);
        load_b(b0, last ? kc0 : (kbase + 4));   // next pair's first step
        mfma_step(b1, buf, 1, 1);
        __builtin_amdgcn_s_setprio(0);

        if (!last) {
            stage(buf ^ 1, 0, nva0, nva1);
            stage(buf ^ 1, 1, nvb0, nvb1);
            // lgkmcnt-only barrier: drain LDS ops, leave global prefetch
            // (vmcnt) in flight across the sync.
            asm volatile("s_waitcnt lgkmcnt(0)" ::: "memory");
            __builtin_amdgcn_s_barrier();
            asm volatile("" ::: "memory");
        }
    }

    // epilogue: raw partial logits, layout [T][KSPLIT][E]
    // C/D: col(expert)=lane&15, row(token)=(lane>>4)*4+reg
    #pragma unroll
    for (int mt = 0; mt < 4; ++mt)
        #pragma unroll
        for (int nt = 0; nt < 2; ++nt)
            #pragma unroll
            for (int r = 0; r < 4; ++r) {
                const int tok = mt * 16 + kq * 4 + r;
                const int e   = wn * 32 + nt * 16 + lm;
                scores[(((size_t)(t0 + tok)) * KSPLIT + ksl) * E + e] = acc[mt][nt][r];
            }

    // ---- split-K fixup: 4th arriving block gates this tile's 64 tokens ----
    __threadfence();                      // release: partials device-visible
    __syncthreads();                      // all threads' stores+fences done
    if (tid == 0)
        sh_last = (atomicAdd(&cnt[mb], 1u) == KSPLIT - 1) ? 1 : 0;
    __syncthreads();
    if (!sh_last) return;
    __threadfence();                      // acquire side

    // gate: one token per wave, 8 rounds; verbatim math from the verified
    // standalone gate kernel (identical reduction order -> identical bits).
    for (int rep = 0; rep < MT / 8; ++rep) {
        const int t = t0 + rep * 8 + wn;

        const float* p = &scores[(size_t)t * (KSPLIT * E) + lane * 4];
        f32x4 s = (f32x4){0.f, 0.f, 0.f, 0.f};
        #pragma unroll
        for (int k = 0; k < KSPLIT; ++k)
            s += *reinterpret_cast<const f32x4*>(p + k * E);
        f32x4 bi = *reinterpret_cast<const f32x4*>(&bias[lane * 4]);

        float sig[4], bsc[4];
        #pragma unroll
        for (int j = 0; j < 4; ++j) {
            sig[j] = 1.0f / (1.0f + expf(-s[j]));
            bsc[j] = sig[j] + bi[j];
        }

        // group score = sum of top-2 biased scores (group = 8 lanes)
        float h01 = fmaxf(bsc[0], bsc[1]), l01 = fminf(bsc[0], bsc[1]);
        float h23 = fmaxf(bsc[2], bsc[3]), l23 = fminf(bsc[2], bsc[3]);
        float m1 = fmaxf(h01, h23);
        float m2 = fmaxf(fminf(h01, h23), fmaxf(l01, l23));
        #pragma unroll
        for (int d = 1; d < 8; d <<= 1) {
            float om1 = __shfl_xor(m1, d);
            float om2 = __shfl_xor(m2, d);
            float nm1 = fmaxf(m1, om1);
            float nm2 = fmaxf(fminf(m1, om1), fmaxf(m2, om2));
            m1 = nm1; m2 = nm2;
        }
        const float gs  = m1 + m2;
        const int   gid = lane >> 3;

        // top-4 groups by rank count (ties -> lowest group index)
        int cntg = 0;
        #pragma unroll
        for (int j = 0; j < N_GROUP; ++j) {
            float gsj = __shfl(gs, j * 8);
            cntg += (gsj > gs || (gsj == gs && j < gid)) ? 1 : 0;
        }
        const bool selg = (cntg < TOPK_GROUP);

        float mbv[4];
        #pragma unroll
        for (int j = 0; j < 4; ++j) mbv[j] = selg ? bsc[j] : -INFINITY;

        // top-8 experts: 8 wave-argmax rounds, all-register
        float wsum = 0.f;
        f32x4 iv0, iv1, wv0, wv1;
        #pragma unroll
        for (int r = 0; r < TOP_K; ++r) {
            float v = mbv[0]; int li = 0;
            if (mbv[1] > v) { v = mbv[1]; li = 1; }
            if (mbv[2] > v) { v = mbv[2]; li = 2; }
            if (mbv[3] > v) { v = mbv[3]; li = 3; }
            int ei = lane * 4 + li;
            #pragma unroll
            for (int d = 1; d < 64; d <<= 1) {
                float ov = __shfl_xor(v, d);
                int   oi = __shfl_xor(ei, d);
                if (ov > v || (ov == v && oi < ei)) { v = ov; ei = oi; }
            }
            const int sub = ei & 3, owner = ei >> 2;
            const float svl = (sub & 2) ? ((sub & 1) ? sig[3] : sig[2])
                                        : ((sub & 1) ? sig[1] : sig[0]);
            const float wr = __shfl(svl, owner);      // UNBIASED score
            #pragma unroll
            for (int j = 0; j < 4; ++j)               // mask winner
                if (lane == owner && j == sub) mbv[j] = -INFINITY;
            wsum += wr;
            if (r < 4) { iv0[r] = (float)ei;     wv0[r] = wr; }
            else       { iv1[r - 4] = (float)ei; wv1[r - 4] = wr; }
        }

        const float scale = 2.5f / wsum;
        #pragma unroll
        for (int j = 0; j < 4; ++j) { wv0[j] *= scale; wv1[j] *= scale; }

        if (lane == 0) {
            float* oi_ = out + (size_t)t * TOP_K;
            float* ow_ = out + (size_t)T_TOTAL * TOP_K + (size_t)t * TOP_K;
            *reinterpret_cast<f32x4*>(oi_)     = iv0;
            *reinterpret_cast<f32x4*>(oi_ + 4) = iv1;
            *reinterpret_cast<f32x4*>(ow_)     = wv0;
            *reinterpret_cast<f32x4*>(ow_ + 4) = wv1;
        }
    }
}

extern "C" void kernel_launch(void* const* d_in, const int* in_sizes, int n_in,
                              void* d_out, int out_size, void* d_ws, size_t ws_size,
                              hipStream_t stream) {
    const float* x    = (const float*)d_in[0];
    const float* w    = (const float*)d_in[1];
    const float* bias = (const float*)d_in[2];
    float* out = (float*)d_out;

    f16*      wf     = (f16*)d_ws;
    float*    scores = (float*)((char*)d_ws + SCORES_OFF);   // 33.6 MB partials
    unsigned* cnt    = (unsigned*)((char*)d_ws + CNT_OFF);   // 128 counters

    hipLaunchKernelGGL(pack_w_kernel, dim3((H / 32) * 16), dim3(64), 0, stream,
                       w, wf, cnt);
    hipLaunchKernelGGL(gemm_kernel, dim3((T_TOTAL / MT) * KSPLIT), dim3(512), 0, stream,
                       x, wf, scores, bias, out, cnt);
}

// Round 4
// 435.339 us; speedup vs baseline: 1.4667x; 1.4667x over previous
//
#include <hip/hip_runtime.h>
#include <math.h>

typedef __attribute__((ext_vector_type(4))) float f32x4;
typedef _Float16 f16;
typedef __attribute__((ext_vector_type(8))) _Float16 f16x8;

// Problem constants (DeepSeek-V3 gate: hidden (4,2048,7168), 256 experts)
constexpr int H       = 7168;
constexpr int E       = 256;
constexpr int T_TOTAL = 8192;     // 4*2048 tokens

constexpr int KSPLIT  = 4;
constexpr int K_SLICE = H / KSPLIT;    // 1792
constexpr int NCH     = K_SLICE / 64;  // 28 chunks of BK=64
constexpr int NPAIR   = NCH / 2;       // 14 barrier periods (BK=128 per sync)
constexpr int MT      = 64;            // tokens per GEMM block (4 mtiles)

constexpr int N_GROUP    = 8;
constexpr int TOPK_GROUP = 4;
constexpr int TOP_K      = 8;

constexpr size_t SCORES_OFF = 8u * 1024 * 1024;   // ws: wf at 0 (7.34MB), scores at 8MB

// ---------------------------------------------------------------------------
// Kernel 1: split w (fp32) into f16 hi/lo in MFMA B-fragment order:
//   wf[((kc*16 + ntile)*2 + s)*512 + lane*8 + j]
//   kc = h>>5, ntile = e>>4, s = 0(hi)/1(lo), lane = ((h>>3)&3)<<4 | (e&15)
// ---------------------------------------------------------------------------
__global__ __launch_bounds__(64) void pack_w_kernel(const float* __restrict__ w,
                                                    f16* __restrict__ wf)
{
    const int l  = threadIdx.x;
    const int nt = blockIdx.x & 15;
    const int kc = blockIdx.x >> 4;
    const int e  = nt * 16 + (l & 15);
    const int h  = kc * 32 + (l >> 4) * 8;
    const float* src = &w[(size_t)e * H + h];
    f32x4 v0 = *reinterpret_cast<const f32x4*>(src);
    f32x4 v1 = *reinterpret_cast<const f32x4*>(src + 4);
    float v[8] = {v0[0], v0[1], v0[2], v0[3], v1[0], v1[1], v1[2], v1[3]};
    f16x8 hi, lo;
    #pragma unroll
    for (int j = 0; j < 8; ++j) {
        f16 h16 = (f16)v[j];
        hi[j] = h16;
        lo[j] = (f16)(v[j] - (float)h16);
    }
    const size_t base = (((size_t)kc * 16 + nt) * 2) * 512 + (size_t)l * 8;
    *reinterpret_cast<f16x8*>(&wf[base])       = hi;
    *reinterpret_cast<f16x8*>(&wf[base + 512]) = lo;
}

// ---------------------------------------------------------------------------
// Kernel 2: router GEMM, f16-split MFMA (acc += Ahi*Bhi + Ahi*Blo + Alo*Bhi).
// Grid: 512 = 64 M-tiles x 4 K-slices (2 blocks/CU); ksl = bid&3 pins one
// 1.84MB wf slice per XCD -> L2-resident weights.
// Block: 512 thr = 8 waves; block tile 64m x 256n.
// R3 change: wave decomposition 4mt x 2nt -> 2mt x 4nt (wave = 32 tokens x
// 64 experts). Same MFMA count & per-accumulator order (bit-identical), but
// A-fragment LDS reads HALVE (each ahi/alo read now feeds 4 nt instead of
// 2): LDS pipe was co-critical with the MFMA pipe (~100%), drops to ~60%.
// B loads double but hit the XCD-pinned L2 slice (aggregate ~0.7 TB/s).
// Barrier = lgkmcnt-only (global prefetch stays in flight); 14 barriers;
// s_setprio(1) around MFMA region. NO fixup fusion (R2's fence storm).
// ---------------------------------------------------------------------------
__global__ __launch_bounds__(512, 4) void gemm_kernel(
    const float* __restrict__ x,      // [T_TOTAL, H] fp32
    const f16*   __restrict__ wf,     // packed B-fragments
    float* __restrict__ scores)       // [T_TOTAL][KSPLIT][E] partial logits
{
    // [buf][half][mtile 0..3][ks 0..1][s 0..1][lane 0..63][j 0..7] = 64 KB
    __shared__ __align__(16) f16 x_lds[2][2][4 * 2 * 2 * 512];

    const int tid  = threadIdx.x;
    const int lane = tid & 63;
    const int wn   = tid >> 6;     // wave 0..7
    const int wg_m = wn >> 2;      // 0..1: token half (mt = wg_m*2 + {0,1})
    const int wg_e = wn & 3;       // 0..3: expert quarter (64 experts)

    const int bid = blockIdx.x;
    const int ksl = bid & 3;
    const int mb  = bid >> 2;      // 0..63
    const int t0  = mb * MT;
    const int k0  = ksl * K_SLICE;
    const int kc0 = k0 >> 5;       // first K-chunk-of-32 index

    // x loader: tid -> (mtile, ks, lane); 8 floats per thread per chunk
    const int lmt = (tid >> 6) & 3;
    const int lks = tid >> 8;                 // 0..1
    const float* xrow = &x[(size_t)(t0 + lmt * 16 + (lane & 15)) * H
                           + k0 + lks * 32 + (lane >> 4) * 8];

    const int lm = lane & 15;
    const int kq = lane >> 4;

    f32x4 acc[2][4];               // [mtl][nt]
    #pragma unroll
    for (int mtl = 0; mtl < 2; ++mtl)
        #pragma unroll
        for (int nt = 0; nt < 4; ++nt)
            acc[mtl][nt] = (f32x4){0.f, 0.f, 0.f, 0.f};

    // stage this thread's 8 floats as hi/lo fragments into LDS
    auto stage = [&](int bu, int half, f32x4 v0, f32x4 v1) {
        float v[8] = {v0[0], v0[1], v0[2], v0[3], v1[0], v1[1], v1[2], v1[3]};
        f16x8 hi, lo;
        #pragma unroll
        for (int j = 0; j < 8; ++j) {
            f16 h16 = (f16)v[j];
            hi[j] = h16;
            lo[j] = (f16)(v[j] - (float)h16);
        }
        f16* base = &x_lds[bu][half][((lmt * 2 + lks) * 2) * 512 + lane * 8];
        *reinterpret_cast<f16x8*>(base)       = hi;
        *reinterpret_cast<f16x8*>(base + 512) = lo;
    };

    // B fragments: 4 ntiles (64 experts) x hi/lo
    auto load_b = [&](f16x8 (&b)[4][2], int kc) {
        #pragma unroll
        for (int nt = 0; nt < 4; ++nt)
            #pragma unroll
            for (int s = 0; s < 2; ++s)
                b[nt][s] = *reinterpret_cast<const f16x8*>(
                    &wf[(((size_t)kc * 16 + wg_e * 4 + nt) * 2 + s) * 512 + lane * 8]);
    };

    // one 32-k step: 2 mtiles x 4 ntiles; per-acc order hihi, hilo, lohi
    // (identical numerics to the verified kernel). 4 ds_read_b128 per step.
    auto mfma_step = [&](const f16x8 (&b)[4][2], int bu, int half, int ks) {
        #pragma unroll
        for (int mtl = 0; mtl < 2; ++mtl) {
            const int mt = wg_m * 2 + mtl;
            const f16* ap = &x_lds[bu][half][((mt * 2 + ks) * 2) * 512 + lane * 8];
            f16x8 ahi = *reinterpret_cast<const f16x8*>(ap);
            f16x8 alo = *reinterpret_cast<const f16x8*>(ap + 512);
            #pragma unroll
            for (int nt = 0; nt < 4; ++nt)
                acc[mtl][nt] = __builtin_amdgcn_mfma_f32_16x16x32_f16(
                    ahi, b[nt][0], acc[mtl][nt], 0, 0, 0);
            #pragma unroll
            for (int nt = 0; nt < 4; ++nt)
                acc[mtl][nt] = __builtin_amdgcn_mfma_f32_16x16x32_f16(
                    ahi, b[nt][1], acc[mtl][nt], 0, 0, 0);
            #pragma unroll
            for (int nt = 0; nt < 4; ++nt)
                acc[mtl][nt] = __builtin_amdgcn_mfma_f32_16x16x32_f16(
                    alo, b[nt][0], acc[mtl][nt], 0, 0, 0);
        }
    };

    f16x8 b0[4][2], b1[4][2];

    // prologue: stage chunks 0,1 into buf 0; preload first B step
    {
        f32x4 v0 = *reinterpret_cast<const f32x4*>(xrow);
        f32x4 v1 = *reinterpret_cast<const f32x4*>(xrow + 4);
        f32x4 v2 = *reinterpret_cast<const f32x4*>(xrow + 64);
        f32x4 v3 = *reinterpret_cast<const f32x4*>(xrow + 68);
        stage(0, 0, v0, v1);
        stage(0, 1, v2, v3);
    }
    load_b(b0, kc0);
    __syncthreads();

    for (int i = 0; i < NPAIR; ++i) {
        const int buf   = i & 1;
        const int kbase = kc0 + i * 4;
        const bool last = (i + 1 == NPAIR);

        // prefetch next pair of x chunks into registers (HBM latency hides
        // under ~2 chunks of MFMA; loads may also span the barrier)
        f32x4 nva0, nva1, nvb0, nvb1;
        if (!last) {
            const float* nx = xrow + (2 * i + 2) * 64;
            nva0 = *reinterpret_cast<const f32x4*>(nx);
            nva1 = *reinterpret_cast<const f32x4*>(nx + 4);
            nvb0 = *reinterpret_cast<const f32x4*>(nx + 64);
            nvb1 = *reinterpret_cast<const f32x4*>(nx + 68);
        }

        // B register pipeline across the 4 K-steps of this pair
        load_b(b1, kbase + 1);
        __builtin_amdgcn_s_setprio(1);
        mfma_step(b0, buf, 0, 0);
        load_b(b0, kbase + 2);
        mfma_step(b1, buf, 0, 1);
        load_b(b1, kbase + 3);
        mfma_step(b0, buf, 1, 0);
        load_b(b0, last ? kc0 : (kbase + 4));   // next pair's first step
        mfma_step(b1, buf, 1, 1);
        __builtin_amdgcn_s_setprio(0);

        if (!last) {
            stage(buf ^ 1, 0, nva0, nva1);
            stage(buf ^ 1, 1, nvb0, nvb1);
            // lgkmcnt-only barrier: drain ds ops, leave global prefetch
            // (vmcnt) in flight across the sync.
            asm volatile("s_waitcnt lgkmcnt(0)" ::: "memory");
            __builtin_amdgcn_s_barrier();
            asm volatile("" ::: "memory");
        }
    }

    // epilogue: raw partial logits, layout [T][KSPLIT][E]
    // C/D: col(expert)=lane&15, row(token)=(lane>>4)*4+reg
    #pragma unroll
    for (int mtl = 0; mtl < 2; ++mtl)
        #pragma unroll
        for (int nt = 0; nt < 4; ++nt)
            #pragma unroll
            for (int r = 0; r < 4; ++r) {
                const int tok = (wg_m * 2 + mtl) * 16 + kq * 4 + r;
                const int e   = wg_e * 64 + nt * 16 + lm;
                scores[(((size_t)(t0 + tok)) * KSPLIT + ksl) * E + e] = acc[mtl][nt][r];
            }
}

// ---------------------------------------------------------------------------
// Kernel 3: reduce K-split partials, sigmoid, grouped top-k gating.
// ONE TOKEN PER WAVE, fully register-resident (unchanged, verified).
// ---------------------------------------------------------------------------
__global__ __launch_bounds__(256) void gate_kernel(
    const float* __restrict__ scores,  // [T_TOTAL][KSPLIT][E]
    const float* __restrict__ bias,    // [E]
    float* __restrict__ out)           // [T*8 idx floats][T*8 weight floats]
{
    const int lane = threadIdx.x & 63;
    const int wv   = threadIdx.x >> 6;            // 0..3
    const int t    = blockIdx.x * 4 + wv;

    // reduce K-split partials: lane l covers experts 4l..4l+3
    const float* p = &scores[(size_t)t * (KSPLIT * E) + lane * 4];
    f32x4 s = (f32x4){0.f, 0.f, 0.f, 0.f};
    #pragma unroll
    for (int k = 0; k < KSPLIT; ++k)
        s += *reinterpret_cast<const f32x4*>(p + k * E);
    f32x4 bi = *reinterpret_cast<const f32x4*>(&bias[lane * 4]);

    float sig[4], bsc[4];
    #pragma unroll
    for (int j = 0; j < 4; ++j) {
        sig[j] = 1.0f / (1.0f + expf(-s[j]));
        bsc[j] = sig[j] + bi[j];
    }

    // ---- group score = sum of top-2 biased scores (group = 8 lanes) ----
    float h01 = fmaxf(bsc[0], bsc[1]), l01 = fminf(bsc[0], bsc[1]);
    float h23 = fmaxf(bsc[2], bsc[3]), l23 = fminf(bsc[2], bsc[3]);
    float m1 = fmaxf(h01, h23);
    float m2 = fmaxf(fminf(h01, h23), fmaxf(l01, l23));
    #pragma unroll
    for (int d = 1; d < 8; d <<= 1) {
        float om1 = __shfl_xor(m1, d);
        float om2 = __shfl_xor(m2, d);
        float nm1 = fmaxf(m1, om1);
        float nm2 = fmaxf(fminf(m1, om1), fmaxf(m2, om2));
        m1 = nm1; m2 = nm2;
    }
    const float gs  = m1 + m2;
    const int   gid = lane >> 3;

    // ---- top-4 groups by rank count (ties -> lowest group index) ----
    int cnt = 0;
    #pragma unroll
    for (int j = 0; j < N_GROUP; ++j) {
        float gsj = __shfl(gs, j * 8);
        cnt += (gsj > gs || (gsj == gs && j < gid)) ? 1 : 0;
    }
    const bool sel = (cnt < TOPK_GROUP);

    float mb[4];
    #pragma unroll
    for (int j = 0; j < 4; ++j) mb[j] = sel ? bsc[j] : -INFINITY;

    // ---- top-8 experts: 8 wave-argmax rounds, all-register ----
    float wsum = 0.f;
    f32x4 iv0, iv1, wv0, wv1;
    #pragma unroll
    for (int r = 0; r < TOP_K; ++r) {
        float v = mb[0]; int li = 0;
        if (mb[1] > v) { v = mb[1]; li = 1; }
        if (mb[2] > v) { v = mb[2]; li = 2; }
        if (mb[3] > v) { v = mb[3]; li = 3; }
        int ei = lane * 4 + li;
        #pragma unroll
        for (int d = 1; d < 64; d <<= 1) {
            float ov = __shfl_xor(v, d);
            int   oi = __shfl_xor(ei, d);
            if (ov > v || (ov == v && oi < ei)) { v = ov; ei = oi; }
        }
        // ei now uniform = argmax with lowest-index tie-break
        const int sub = ei & 3, owner = ei >> 2;
        const float svl = (sub & 2) ? ((sub & 1) ? sig[3] : sig[2])
                                    : ((sub & 1) ? sig[1] : sig[0]);
        const float wr = __shfl(svl, owner);      // UNBIASED score
        #pragma unroll
        for (int j = 0; j < 4; ++j)               // mask winner (static idx)
            if (lane == owner && j == sub) mb[j] = -INFINITY;
        wsum += wr;
        if (r < 4) { iv0[r] = (float)ei;     wv0[r] = wr; }
        else       { iv1[r - 4] = (float)ei; wv1[r - 4] = wr; }
    }

    const float scale = 2.5f / wsum;
    #pragma unroll
    for (int j = 0; j < 4; ++j) { wv0[j] *= scale; wv1[j] *= scale; }

    if (lane == 0) {
        float* oi_ = out + (size_t)t * TOP_K;
        float* ow_ = out + (size_t)T_TOTAL * TOP_K + (size_t)t * TOP_K;
        *reinterpret_cast<f32x4*>(oi_)     = iv0;
        *reinterpret_cast<f32x4*>(oi_ + 4) = iv1;
        *reinterpret_cast<f32x4*>(ow_)     = wv0;
        *reinterpret_cast<f32x4*>(ow_ + 4) = wv1;
    }
}

extern "C" void kernel_launch(void* const* d_in, const int* in_sizes, int n_in,
                              void* d_out, int out_size, void* d_ws, size_t ws_size,
                              hipStream_t stream) {
    const float* x    = (const float*)d_in[0];
    const float* w    = (const float*)d_in[1];
    const float* bias = (const float*)d_in[2];
    float* out = (float*)d_out;

    f16*   wf     = (f16*)d_ws;
    float* scores = (float*)((char*)d_ws + SCORES_OFF);   // 33.6 MB partials

    hipLaunchKernelGGL(pack_w_kernel, dim3((H / 32) * 16), dim3(64), 0, stream, w, wf);
    hipLaunchKernelGGL(gemm_kernel, dim3((T_TOTAL / MT) * KSPLIT), dim3(512), 0, stream,
                       x, wf, scores);
    hipLaunchKernelGGL(gate_kernel, dim3(T_TOTAL / 4), dim3(256), 0, stream,
                       scores, bias, out);
}

// Round 5
// 366.774 us; speedup vs baseline: 1.7409x; 1.1869x over previous
//
#include <hip/hip_runtime.h>
#include <math.h>

typedef __attribute__((ext_vector_type(4))) float f32x4;
typedef _Float16 f16;
typedef __attribute__((ext_vector_type(8))) _Float16 f16x8;

// Problem constants (DeepSeek-V3 gate: hidden (4,2048,7168), 256 experts)
constexpr int H       = 7168;
constexpr int E       = 256;
constexpr int T_TOTAL = 8192;     // 4*2048 tokens

constexpr int KSPLIT  = 4;
constexpr int K_SLICE = H / KSPLIT;    // 1792
constexpr int NCH     = K_SLICE / 64;  // 28 chunks of BK=64
constexpr int NPAIR   = NCH / 2;       // 14 barrier periods (BK=128 per sync)
constexpr int NKC     = K_SLICE / 32;  // 56 K-steps of 32
constexpr int MT      = 64;            // tokens per GEMM block (4 mtiles)

constexpr int N_GROUP    = 8;
constexpr int TOPK_GROUP = 4;
constexpr int TOP_K      = 8;

constexpr size_t SCORES_OFF = 8u * 1024 * 1024;   // ws: wf at 0 (7.34MB), scores at 8MB

// ---------------------------------------------------------------------------
// Kernel 1: split w (fp32) into f16 hi/lo in MFMA B-fragment order:
//   wf[((kc*16 + ntile)*2 + s)*512 + lane*8 + j]
//   kc = h>>5, ntile = e>>4, s = 0(hi)/1(lo), lane = ((h>>3)&3)<<4 | (e&15)
// ---------------------------------------------------------------------------
__global__ __launch_bounds__(64) void pack_w_kernel(const float* __restrict__ w,
                                                    f16* __restrict__ wf)
{
    const int l  = threadIdx.x;
    const int nt = blockIdx.x & 15;
    const int kc = blockIdx.x >> 4;
    const int e  = nt * 16 + (l & 15);
    const int h  = kc * 32 + (l >> 4) * 8;
    const float* src = &w[(size_t)e * H + h];
    f32x4 v0 = *reinterpret_cast<const f32x4*>(src);
    f32x4 v1 = *reinterpret_cast<const f32x4*>(src + 4);
    float v[8] = {v0[0], v0[1], v0[2], v0[3], v1[0], v1[1], v1[2], v1[3]};
    f16x8 hi, lo;
    #pragma unroll
    for (int j = 0; j < 8; ++j) {
        f16 h16 = (f16)v[j];
        hi[j] = h16;
        lo[j] = (f16)(v[j] - (float)h16);
    }
    const size_t base = (((size_t)kc * 16 + nt) * 2) * 512 + (size_t)l * 8;
    *reinterpret_cast<f16x8*>(&wf[base])       = hi;
    *reinterpret_cast<f16x8*>(&wf[base + 512]) = lo;
}

// ---------------------------------------------------------------------------
// Kernel 2: router GEMM, f16-split MFMA (acc += Ahi*Bhi + Ahi*Blo + Alo*Bhi).
// Grid: 512 = 64 M-tiles x 4 K-slices (2 blocks/CU); ksl = bid&3 pins one
// 1.84MB wf slice per XCD -> L2-resident weights.
// Block: 512 thr = 8 waves; block tile 64m x 256n; wave tile 64m x 32n
// (4 mtiles x 2 ntiles -- R4's 2x4 reshape REGRESSED (193us, latency-bound
// on doubled per-wave L2 B-traffic) and is reverted).
// R5 change vs R1: B register pipeline deepened from depth-1 to DEPTH-3 via
// a 4-slot rotating buffer (slot = K-step & 3 -> static indexing). B loads
// are issued 3 mfma_steps (~350+ cyc) before consumption, covering L2-hit
// latency (~200-225 cyc) that previously stalled every step (~100-300 cyc
// vmcnt wait with only 1 step of cover). K-step order and per-accumulator
// MFMA order (hihi, hilo, lohi) unchanged -> bit-identical numerics.
// 14 lgkm-only barriers (global prefetch stays in flight); setprio around
// the MFMA region.
// ---------------------------------------------------------------------------
__global__ __launch_bounds__(512, 4) void gemm_kernel(
    const float* __restrict__ x,      // [T_TOTAL, H] fp32
    const f16*   __restrict__ wf,     // packed B-fragments
    float* __restrict__ scores)       // [T_TOTAL][KSPLIT][E] partial logits
{
    // [buf][half][mtile 0..3][ks 0..1][s 0..1][lane 0..63][j 0..7] = 64 KB
    __shared__ __align__(16) f16 x_lds[2][2][4 * 2 * 2 * 512];

    const int tid  = threadIdx.x;
    const int lane = tid & 63;
    const int wn   = tid >> 6;     // wave 0..7: experts wn*32 .. +31

    const int bid = blockIdx.x;
    const int ksl = bid & 3;
    const int mb  = bid >> 2;      // 0..63
    const int t0  = mb * MT;
    const int k0  = ksl * K_SLICE;
    const int kc0 = k0 >> 5;       // first K-chunk-of-32 index

    // x loader: tid -> (mtile, ks, lane); 8 floats per thread per chunk
    const int lmt = (tid >> 6) & 3;
    const int lks = tid >> 8;                 // 0..1
    const float* xrow = &x[(size_t)(t0 + lmt * 16 + (lane & 15)) * H
                           + k0 + lks * 32 + (lane >> 4) * 8];

    const int lm = lane & 15;
    const int kq = lane >> 4;

    f32x4 acc[4][2];
    #pragma unroll
    for (int mt = 0; mt < 4; ++mt)
        #pragma unroll
        for (int nt = 0; nt < 2; ++nt)
            acc[mt][nt] = (f32x4){0.f, 0.f, 0.f, 0.f};

    // stage this thread's 8 floats as hi/lo fragments into LDS
    auto stage = [&](int bu, int half, f32x4 v0, f32x4 v1) {
        float v[8] = {v0[0], v0[1], v0[2], v0[3], v1[0], v1[1], v1[2], v1[3]};
        f16x8 hi, lo;
        #pragma unroll
        for (int j = 0; j < 8; ++j) {
            f16 h16 = (f16)v[j];
            hi[j] = h16;
            lo[j] = (f16)(v[j] - (float)h16);
        }
        f16* base = &x_lds[bu][half][((lmt * 2 + lks) * 2) * 512 + lane * 8];
        *reinterpret_cast<f16x8*>(base)       = hi;
        *reinterpret_cast<f16x8*>(base + 512) = lo;
    };

    auto load_b = [&](f16x8 (&b)[2][2], int kc) {
        #pragma unroll
        for (int nt = 0; nt < 2; ++nt)
            #pragma unroll
            for (int s = 0; s < 2; ++s)
                b[nt][s] = *reinterpret_cast<const f16x8*>(
                    &wf[(((size_t)kc * 16 + wn * 2 + nt) * 2 + s) * 512 + lane * 8]);
    };

    // per-mtile A fragments (8 transient VGPRs); per-acc order is
    // hihi, hilo, lohi within each 32-k step (identical numerics)
    auto mfma_step = [&](const f16x8 (&b)[2][2], int bu, int half, int ks) {
        #pragma unroll
        for (int mt = 0; mt < 4; ++mt) {
            const f16* ap = &x_lds[bu][half][((mt * 2 + ks) * 2) * 512 + lane * 8];
            f16x8 ahi = *reinterpret_cast<const f16x8*>(ap);
            f16x8 alo = *reinterpret_cast<const f16x8*>(ap + 512);
            acc[mt][0] = __builtin_amdgcn_mfma_f32_16x16x32_f16(ahi, b[0][0], acc[mt][0], 0, 0, 0);
            acc[mt][1] = __builtin_amdgcn_mfma_f32_16x16x32_f16(ahi, b[1][0], acc[mt][1], 0, 0, 0);
            acc[mt][0] = __builtin_amdgcn_mfma_f32_16x16x32_f16(ahi, b[0][1], acc[mt][0], 0, 0, 0);
            acc[mt][1] = __builtin_amdgcn_mfma_f32_16x16x32_f16(ahi, b[1][1], acc[mt][1], 0, 0, 0);
            acc[mt][0] = __builtin_amdgcn_mfma_f32_16x16x32_f16(alo, b[0][0], acc[mt][0], 0, 0, 0);
            acc[mt][1] = __builtin_amdgcn_mfma_f32_16x16x32_f16(alo, b[1][0], acc[mt][1], 0, 0, 0);
        }
    };

    // 4-slot rotating B buffer; slot index = K-step & 3 (static per unrolled
    // position: pair i, step s -> slot s). Prefetch depth 3.
    f16x8 B0[2][2], B1[2][2], B2[2][2], B3[2][2];

    // prologue: stage chunks 0,1 into buf 0; preload B steps 0,1,2
    {
        f32x4 v0 = *reinterpret_cast<const f32x4*>(xrow);
        f32x4 v1 = *reinterpret_cast<const f32x4*>(xrow + 4);
        f32x4 v2 = *reinterpret_cast<const f32x4*>(xrow + 64);
        f32x4 v3 = *reinterpret_cast<const f32x4*>(xrow + 68);
        stage(0, 0, v0, v1);
        stage(0, 1, v2, v3);
    }
    load_b(B0, kc0);
    load_b(B1, kc0 + 1);
    load_b(B2, kc0 + 2);
    __syncthreads();

    for (int i = 0; i < NPAIR; ++i) {
        const int buf   = i & 1;
        const int g     = i * 4;            // global K-step of this pair
        const int kbase = kc0 + g;
        const bool last = (i + 1 == NPAIR);

        // prefetch next pair of x chunks into registers (HBM/L3 latency
        // hides under 4 mfma_steps; loads may also span the barrier)
        f32x4 nva0, nva1, nvb0, nvb1;
        if (!last) {
            const float* nx = xrow + (2 * i + 2) * 64;
            nva0 = *reinterpret_cast<const f32x4*>(nx);
            nva1 = *reinterpret_cast<const f32x4*>(nx + 4);
            nvb0 = *reinterpret_cast<const f32x4*>(nx + 64);
            nvb1 = *reinterpret_cast<const f32x4*>(nx + 68);
        }

        // depth-3 B pipeline across the 4 K-steps of this pair:
        // consume slot s, issue load for step g+s+3 into slot (s+3)&3.
        __builtin_amdgcn_s_setprio(1);
        load_b(B3, (g + 3 < NKC) ? (kbase + 3) : kc0);
        mfma_step(B0, buf, 0, 0);
        load_b(B0, (g + 4 < NKC) ? (kbase + 4) : kc0);
        mfma_step(B1, buf, 0, 1);
        load_b(B1, (g + 5 < NKC) ? (kbase + 5) : kc0);
        mfma_step(B2, buf, 1, 0);
        load_b(B2, (g + 6 < NKC) ? (kbase + 6) : kc0);
        mfma_step(B3, buf, 1, 1);
        __builtin_amdgcn_s_setprio(0);

        if (!last) {
            stage(buf ^ 1, 0, nva0, nva1);
            stage(buf ^ 1, 1, nvb0, nvb1);
            // lgkmcnt-only barrier: drain ds ops, leave global prefetch
            // (vmcnt) in flight across the sync.
            asm volatile("s_waitcnt lgkmcnt(0)" ::: "memory");
            __builtin_amdgcn_s_barrier();
            asm volatile("" ::: "memory");
        }
    }

    // epilogue: raw partial logits, layout [T][KSPLIT][E]
    // C/D: col(expert)=lane&15, row(token)=(lane>>4)*4+reg
    #pragma unroll
    for (int mt = 0; mt < 4; ++mt)
        #pragma unroll
        for (int nt = 0; nt < 2; ++nt)
            #pragma unroll
            for (int r = 0; r < 4; ++r) {
                const int tok = mt * 16 + kq * 4 + r;
                const int e   = wn * 32 + nt * 16 + lm;
                scores[(((size_t)(t0 + tok)) * KSPLIT + ksl) * E + e] = acc[mt][nt][r];
            }
}

// ---------------------------------------------------------------------------
// Kernel 3: reduce K-split partials, sigmoid, grouped top-k gating.
// ONE TOKEN PER WAVE, fully register-resident (unchanged, verified).
// ---------------------------------------------------------------------------
__global__ __launch_bounds__(256) void gate_kernel(
    const float* __restrict__ scores,  // [T_TOTAL][KSPLIT][E]
    const float* __restrict__ bias,    // [E]
    float* __restrict__ out)           // [T*8 idx floats][T*8 weight floats]
{
    const int lane = threadIdx.x & 63;
    const int wv   = threadIdx.x >> 6;            // 0..3
    const int t    = blockIdx.x * 4 + wv;

    // reduce K-split partials: lane l covers experts 4l..4l+3
    const float* p = &scores[(size_t)t * (KSPLIT * E) + lane * 4];
    f32x4 s = (f32x4){0.f, 0.f, 0.f, 0.f};
    #pragma unroll
    for (int k = 0; k < KSPLIT; ++k)
        s += *reinterpret_cast<const f32x4*>(p + k * E);
    f32x4 bi = *reinterpret_cast<const f32x4*>(&bias[lane * 4]);

    float sig[4], bsc[4];
    #pragma unroll
    for (int j = 0; j < 4; ++j) {
        sig[j] = 1.0f / (1.0f + expf(-s[j]));
        bsc[j] = sig[j] + bi[j];
    }

    // ---- group score = sum of top-2 biased scores (group = 8 lanes) ----
    float h01 = fmaxf(bsc[0], bsc[1]), l01 = fminf(bsc[0], bsc[1]);
    float h23 = fmaxf(bsc[2], bsc[3]), l23 = fminf(bsc[2], bsc[3]);
    float m1 = fmaxf(h01, h23);
    float m2 = fmaxf(fminf(h01, h23), fmaxf(l01, l23));
    #pragma unroll
    for (int d = 1; d < 8; d <<= 1) {
        float om1 = __shfl_xor(m1, d);
        float om2 = __shfl_xor(m2, d);
        float nm1 = fmaxf(m1, om1);
        float nm2 = fmaxf(fminf(m1, om1), fmaxf(m2, om2));
        m1 = nm1; m2 = nm2;
    }
    const float gs  = m1 + m2;
    const int   gid = lane >> 3;

    // ---- top-4 groups by rank count (ties -> lowest group index) ----
    int cnt = 0;
    #pragma unroll
    for (int j = 0; j < N_GROUP; ++j) {
        float gsj = __shfl(gs, j * 8);
        cnt += (gsj > gs || (gsj == gs && j < gid)) ? 1 : 0;
    }
    const bool sel = (cnt < TOPK_GROUP);

    float mb[4];
    #pragma unroll
    for (int j = 0; j < 4; ++j) mb[j] = sel ? bsc[j] : -INFINITY;

    // ---- top-8 experts: 8 wave-argmax rounds, all-register ----
    float wsum = 0.f;
    f32x4 iv0, iv1, wv0, wv1;
    #pragma unroll
    for (int r = 0; r < TOP_K; ++r) {
        float v = mb[0]; int li = 0;
        if (mb[1] > v) { v = mb[1]; li = 1; }
        if (mb[2] > v) { v = mb[2]; li = 2; }
        if (mb[3] > v) { v = mb[3]; li = 3; }
        int ei = lane * 4 + li;
        #pragma unroll
        for (int d = 1; d < 64; d <<= 1) {
            float ov = __shfl_xor(v, d);
            int   oi = __shfl_xor(ei, d);
            if (ov > v || (ov == v && oi < ei)) { v = ov; ei = oi; }
        }
        // ei now uniform = argmax with lowest-index tie-break
        const int sub = ei & 3, owner = ei >> 2;
        const float svl = (sub & 2) ? ((sub & 1) ? sig[3] : sig[2])
                                    : ((sub & 1) ? sig[1] : sig[0]);
        const float wr = __shfl(svl, owner);      // UNBIASED score
        #pragma unroll
        for (int j = 0; j < 4; ++j)               // mask winner (static idx)
            if (lane == owner && j == sub) mb[j] = -INFINITY;
        wsum += wr;
        if (r < 4) { iv0[r] = (float)ei;     wv0[r] = wr; }
        else       { iv1[r - 4] = (float)ei; wv1[r - 4] = wr; }
    }

    const float scale = 2.5f / wsum;
    #pragma unroll
    for (int j = 0; j < 4; ++j) { wv0[j] *= scale; wv1[j] *= scale; }

    if (lane == 0) {
        float* oi_ = out + (size_t)t * TOP_K;
        float* ow_ = out + (size_t)T_TOTAL * TOP_K + (size_t)t * TOP_K;
        *reinterpret_cast<f32x4*>(oi_)     = iv0;
        *reinterpret_cast<f32x4*>(oi_ + 4) = iv1;
        *reinterpret_cast<f32x4*>(ow_)     = wv0;
        *reinterpret_cast<f32x4*>(ow_ + 4) = wv1;
    }
}

extern "C" void kernel_launch(void* const* d_in, const int* in_sizes, int n_in,
                              void* d_out, int out_size, void* d_ws, size_t ws_size,
                              hipStream_t stream) {
    const float* x    = (const float*)d_in[0];
    const float* w    = (const float*)d_in[1];
    const float* bias = (const float*)d_in[2];
    float* out = (float*)d_out;

    f16*   wf     = (f16*)d_ws;
    float* scores = (float*)((char*)d_ws + SCORES_OFF);   // 33.6 MB partials

    hipLaunchKernelGGL(pack_w_kernel, dim3((H / 32) * 16), dim3(64), 0, stream, w, wf);
    hipLaunchKernelGGL(gemm_kernel, dim3((T_TOTAL / MT) * KSPLIT), dim3(512), 0, stream,
                       x, wf, scores);
    hipLaunchKernelGGL(gate_kernel, dim3(T_TOTAL / 4), dim3(256), 0, stream,
                       scores, bias, out);
}